// Round 1
// baseline (108.131 us; speedup 1.0000x reference)
//
#include <hip/hip_runtime.h>

#define NORB 96
#define NN 9216  // 96*96

// ---------------------------------------------------------------------------
// zero-init kernel (d_ws is poisoned 0xAA and never re-poisoned between
// replays, so K must be zeroed inside the graph every call)
// ---------------------------------------------------------------------------
__global__ void zero_kernel(float* __restrict__ p, int n) {
  int i = blockIdx.x * blockDim.x + threadIdx.x;
  if (i < n) p[i] = 0.f;
}

// ---------------------------------------------------------------------------
// Single streaming pass over eri computing BOTH
//   J[a][b] = sum_{c,d} P[c][d] * eri[a][b][c][d]
//   K[b][d] = sum_{a,c} P[a][c] * eri[a][b][c][d]
// One block per (a,b) slab (9216 contiguous floats = 36 KB).
// 192 threads: x = tid%24 -> float4 column group (d = 4x..4x+3),
//              y = tid/24 -> c stride group (c = y, y+8, ...).
// ---------------------------------------------------------------------------
__global__ __launch_bounds__(192) void jk_kernel(
    const float* __restrict__ eri, const float* __restrict__ P,
    float* __restrict__ Jm, float* __restrict__ Km) {
  const int ab = blockIdx.x;
  const int a = ab / NORB;
  const int b = ab - a * NORB;
  const float4* slab4 = (const float4*)(eri + (size_t)ab * NN);
  const float4* P4 = (const float4*)P;
  const int tid = threadIdx.x;
  const int x = tid % 24;
  const int y = tid / 24;  // 0..7

  float jp = 0.f;
  float k0 = 0.f, k1 = 0.f, k2 = 0.f, k3 = 0.f;
#pragma unroll 4
  for (int c = y; c < NORB; c += 8) {
    float4 v = slab4[c * 24 + x];
    float4 pv = P4[c * 24 + x];
    float pa = P[a * NORB + c];
    jp += v.x * pv.x + v.y * pv.y + v.z * pv.z + v.w * pv.w;
    k0 += pa * v.x;
    k1 += pa * v.y;
    k2 += pa * v.z;
    k3 += pa * v.w;
  }

  __shared__ float kl[NORB];
  __shared__ float js[3];
  if (tid < NORB) kl[tid] = 0.f;
  __syncthreads();
  atomicAdd(&kl[x * 4 + 0], k0);
  atomicAdd(&kl[x * 4 + 1], k1);
  atomicAdd(&kl[x * 4 + 2], k2);
  atomicAdd(&kl[x * 4 + 3], k3);

  // J: block-wide sum (3 waves)
#pragma unroll
  for (int off = 32; off; off >>= 1) jp += __shfl_down(jp, off);
  if ((tid & 63) == 0) js[tid >> 6] = jp;
  __syncthreads();
  if (tid == 0) Jm[ab] = js[0] + js[1] + js[2];
  if (tid < NORB) atomicAdd(&Km[b * NORB + tid], kl[tid]);
}

// ---------------------------------------------------------------------------
// C[i][j] = sum_k A[i][k] * B[k][j]   (96x96, one block per row)
// ---------------------------------------------------------------------------
__global__ __launch_bounds__(128) void gemm_nn_96(
    const float* __restrict__ A, const float* __restrict__ B,
    float* __restrict__ C) {
  const int i = blockIdx.x;
  const int j = threadIdx.x;
  __shared__ float arow[NORB];
  if (j < NORB) arow[j] = A[i * NORB + j];
  __syncthreads();
  if (j < NORB) {
    float acc = 0.f;
    for (int k = 0; k < NORB; ++k) acc += arow[k] * B[k * NORB + j];
    C[i * NORB + j] = acc;
  }
}

// C[i][j] = sum_k A[i][k] * B[j][k]   (A @ B^T)
__global__ __launch_bounds__(128) void gemm_nt_96(
    const float* __restrict__ A, const float* __restrict__ B,
    float* __restrict__ C) {
  const int i = blockIdx.x;
  const int j = threadIdx.x;
  __shared__ float arow[NORB];
  if (j < NORB) arow[j] = A[i * NORB + j];
  __syncthreads();
  if (j < NORB) {
    float acc = 0.f;
    for (int k = 0; k < NORB; ++k) acc += arow[k] * B[j * NORB + k];
    C[i * NORB + j] = acc;
  }
}

// ---------------------------------------------------------------------------
// Per-row LayerNorm + QKV projection: qkv[i][j] = sum_c xn[i][c]*Wqkv[c][j]
// One block per row i; 128 threads; each thread produces 3 outputs.
// ---------------------------------------------------------------------------
__global__ __launch_bounds__(128) void ln_qkv_kernel(
    const float* __restrict__ x, const float* __restrict__ ln_s,
    const float* __restrict__ ln_b, const float* __restrict__ Wqkv,
    float* __restrict__ qkv) {
  const int i = blockIdx.x;
  const int t = threadIdx.x;  // 0..127
  __shared__ float xn[128];
  __shared__ float red[2];

  float v = x[i * 128 + t];
  float s = v;
#pragma unroll
  for (int off = 32; off; off >>= 1) s += __shfl_down(s, off);
  if ((t & 63) == 0) red[t >> 6] = s;
  __syncthreads();
  const float mu = (red[0] + red[1]) * (1.f / 128.f);
  __syncthreads();
  const float dv = v - mu;
  s = dv * dv;
#pragma unroll
  for (int off = 32; off; off >>= 1) s += __shfl_down(s, off);
  if ((t & 63) == 0) red[t >> 6] = s;
  __syncthreads();
  const float var = (red[0] + red[1]) * (1.f / 128.f);
  xn[t] = dv * rsqrtf(var + 1e-6f) * ln_s[t] + ln_b[t];
  __syncthreads();

#pragma unroll
  for (int jj = 0; jj < 3; ++jj) {
    const int j = t + jj * 128;
    float acc = 0.f;
    for (int c = 0; c < 128; ++c) acc += xn[c] * Wqkv[c * 384 + j];
    qkv[i * 384 + j] = acc;
  }
}

// ---------------------------------------------------------------------------
// Biased multi-head attention. One block per (row i, head h) = 1536 blocks.
// score_j = dot8(q_i, k_j)/sqrt(8) + bias_h[i][j]; softmax over j; out = P@V.
// ---------------------------------------------------------------------------
__global__ __launch_bounds__(128) void attn_kernel(
    const float* __restrict__ qkv, const float* __restrict__ Hc,
    const float* __restrict__ Jm, const float* __restrict__ Km,
    const float* __restrict__ Lm, float* __restrict__ aout) {
  const int i = blockIdx.x >> 4;
  const int h = blockIdx.x & 15;
  const int t = threadIdx.x;  // 0..127
  __shared__ float q_sh[8];
  __shared__ float p[NORB];
  __shared__ float redm[2];
  __shared__ float reds[2];
  __shared__ float pvred[16][8];

  if (t < 8) q_sh[t] = qkv[i * 384 + h * 8 + t];
  __syncthreads();

  float score = -1e30f;
  if (t < NORB) {
    const float* kr = qkv + t * 384 + 128 + h * 8;
    float d = 0.f;
#pragma unroll
    for (int dd = 0; dd < 8; ++dd) d += q_sh[dd] * kr[dd];
    d *= 0.3535533905932738f;  // 1/sqrt(8)
    const int ij = i * NORB + t;
    if (h < 2) d += Hc[ij];
    else if (h < 4) d += Jm[ij] - 0.5f * Km[ij];
    else if (h < 6) d += Lm[ij];
    score = d;
  }

  // block max
  float m = score;
#pragma unroll
  for (int off = 32; off; off >>= 1) m = fmaxf(m, __shfl_down(m, off));
  if ((t & 63) == 0) redm[t >> 6] = m;
  __syncthreads();
  m = fmaxf(redm[0], redm[1]);

  // exp + block sum
  float e = (t < NORB) ? __expf(score - m) : 0.f;
  float s = e;
#pragma unroll
  for (int off = 32; off; off >>= 1) s += __shfl_down(s, off);
  if ((t & 63) == 0) reds[t >> 6] = s;
  if (t < NORB) p[t] = e;
  __syncthreads();
  const float denom = reds[0] + reds[1];

  // PV: thread (g, dd) sums j = g, g+16, ...
  const int dd = t & 7;
  const int g = t >> 3;  // 0..15
  float acc = 0.f;
  for (int j = g; j < NORB; j += 16) acc += p[j] * qkv[j * 384 + 256 + h * 8 + dd];
  pvred[g][dd] = acc;
  __syncthreads();
  if (t < 8) {
    float o = 0.f;
#pragma unroll
    for (int g2 = 0; g2 < 16; ++g2) o += pvred[g2][t];
    aout[i * 128 + h * 8 + t] = o / denom;
  }
}

// ---------------------------------------------------------------------------
// Final projection: y[i][j] = bout[j] + sum_c aout[i][c] * Wout[c][j]
// ---------------------------------------------------------------------------
__global__ __launch_bounds__(128) void out_proj_kernel(
    const float* __restrict__ aout, const float* __restrict__ Wout,
    const float* __restrict__ bout, float* __restrict__ y) {
  const int i = blockIdx.x;
  const int j = threadIdx.x;  // 0..127
  __shared__ float row[128];
  row[j] = aout[i * 128 + j];
  __syncthreads();
  float acc = bout[j];
  for (int c = 0; c < 128; ++c) acc += row[c] * Wout[c * 128 + j];
  y[i * 128 + j] = acc;
}

// ---------------------------------------------------------------------------
extern "C" void kernel_launch(void* const* d_in, const int* in_sizes, int n_in,
                              void* d_out, int out_size, void* d_ws,
                              size_t ws_size, hipStream_t stream) {
  const float* x    = (const float*)d_in[0];
  const float* Hc   = (const float*)d_in[1];
  const float* X    = (const float*)d_in[2];
  const float* eri  = (const float*)d_in[3];
  const float* P    = (const float*)d_in[4];
  const float* ln_s = (const float*)d_in[5];
  const float* ln_b = (const float*)d_in[6];
  const float* Wqkv = (const float*)d_in[7];
  const float* Wout = (const float*)d_in[8];
  const float* bout = (const float*)d_in[9];
  float* y = (float*)d_out;

  float* ws   = (float*)d_ws;
  float* Jm   = ws;                 // 9216
  float* Km   = ws + NN;            // 9216
  float* tmp  = ws + 2 * NN;        // 9216
  float* Lm   = ws + 3 * NN;        // 9216
  float* qkv  = ws + 4 * NN;        // 96*384 = 36864
  float* aout = qkv + 96 * 384;     // 96*128 = 12288

  // K accumulator must be zeroed every call (ws poisoned once, not restored)
  zero_kernel<<<(NN + 255) / 256, 256, 0, stream>>>(Km, NN);

  // dominant pass: stream eri once, produce J and K
  jk_kernel<<<NN, 192, 0, stream>>>(eri, P, Jm, Km);

  // L = X @ H_core @ X^T
  gemm_nn_96<<<NORB, 128, 0, stream>>>(X, Hc, tmp);
  gemm_nt_96<<<NORB, 128, 0, stream>>>(tmp, X, Lm);

  // LayerNorm + QKV projection
  ln_qkv_kernel<<<NORB, 128, 0, stream>>>(x, ln_s, ln_b, Wqkv, qkv);

  // biased attention
  attn_kernel<<<NORB * 16, 128, 0, stream>>>(qkv, Hc, Jm, Km, Lm, aout);

  // output projection
  out_proj_kernel<<<NORB, 128, 0, stream>>>(aout, Wout, bout, y);
}